// Round 8
// baseline (530.906 us; speedup 1.0000x reference)
//
#include <hip/hip_runtime.h>

#define CIN   256
#define COUT  512
#define HW    1024     // H*W = 32*32
#define ITERS 20

typedef __attribute__((ext_vector_type(8)))  short bf16x8;
typedef __attribute__((ext_vector_type(4)))  float f32x4;
typedef __attribute__((ext_vector_type(16))) float f32x16;
typedef __attribute__((ext_vector_type(2)))  unsigned u32x2;

__device__ __forceinline__ unsigned short f2b(float x) {
  unsigned b = __builtin_bit_cast(unsigned, x);
  unsigned r = (b + 0x7FFFu + ((b >> 16) & 1u)) >> 16;   // RNE
  return (unsigned short)r;
}
// packed f32x2 -> bf16x2 (RNE), lo = a, hi = b
__device__ __forceinline__ unsigned cvt_pk_bf16(float a, float b) {
  unsigned r;
  asm("v_cvt_pk_bf16_f32 %0, %1, %2" : "=v"(r) : "v"(a), "v"(b));
  return r;
}

// 32x32x16 MFMA fragment conventions (gfx950):
//  A-frag: lane l holds row m = l&31,  k = (l>>5)*8 + i  (i=0..7)
//  B-frag: lane l holds col n = l&31,  k = (l>>5)*8 + i
//  C/D   : col = lane&31, row = (r&3) + 8*(r>>2) + 4*(lane>>5), r in [0,16)
//
// Both GEMMs computed TRANSPOSED (A = weights, B = h/y, cols = pixels).
//
// w1: GEMM1 A-frags [ct:8][kt:32][lane:64][i:8];  c = ct*32+(l&31), j = kt*16+(l>>5)*8+i
// w2: GEMM2 A-frags [jt:16][kt:16][lane:64][i:8]; j = jt*32+(l&31), c = kt*16+(l>>5)*8+i
__global__ __launch_bounds__(256) void prep_weights(const float* __restrict__ w,
                                                    unsigned short* __restrict__ w1,
                                                    unsigned short* __restrict__ w2) {
  int f = blockIdx.x * 256 + threadIdx.x;   // [0, 131072)
  {
    int i = f & 7, l = (f >> 3) & 63, kt = (f >> 9) & 31, ct = f >> 14;
    int c = ct * 32 + (l & 31);
    int j = kt * 16 + ((l >> 5) << 3) + i;
    w1[f] = f2b(w[j * CIN + c]);
  }
  {
    int i = f & 7, l = (f >> 3) & 63, kt = (f >> 9) & 15, jt = f >> 13;
    int j = jt * 32 + (l & 31);
    int c = kt * 16 + ((l >> 5) << 3) + i;
    w2[f] = f2b(w[j * CIN + c]);
  }
}

// R8: 32 px / 512 threads / 8 waves per block; 2 INDEPENDENT blocks per CU
// (LDS 65.5KB), 4 waves/SIMD total. Same state-light wave shape as R7 (hreg 32,
// x in LDS, acc<=32 AGPR -> 64 arch VGPR, spill-free at the 128-unified cap).
// R7 analysis: ~66% stall; LDS pipe 43% (B-frags read 16x), L2 weights ~32%,
// 3 all-wave barriers per iter serialize the whole CU. Two independent blocks
// decorrelate barrier phases (block A drains while block B issues), and halve
// the B-frag read redundancy (8 waves share a buffer, not 16).
//   GEMM1: wave owns ct = wv (8 ct = 8 waves), 1 px-tile, acc1 = 16 AGPR.
//   GEMM2: wave owns jt pair {2wv, 2wv+1}, acc2 = 32 AGPR.
// Cost: weight L2 traffic 7.7 -> 10.5 GB (~60% of L2 ceiling) — accepted.
__global__ __launch_bounds__(512, 4) void nnmf_kernel(const float* __restrict__ xin,
                                                      const unsigned short* __restrict__ w1,
                                                      const unsigned short* __restrict__ w2,
                                                      float* __restrict__ out) {
  __shared__ __align__(16) unsigned short hA[32 * 512]; // 32KB  B-frags GEMM1 (k=j)
  __shared__ __align__(16) unsigned short yF[16 * 512]; // 16KB  B-frags GEMM2 (k=c)
  __shared__ __align__(16) unsigned xS[8 * 4 * 2 * 32 * 2]; // 16KB bf16 x, [ct][rb][hi][px][2]
  __shared__ float red[32 * 12];                        // 1.5KB per-px partials, stride 12

  const int tid  = threadIdx.x;
  const int wv   = tid >> 6;      // 0..7
  const int lane = tid & 63;
  const int px   = lane & 31;     // pixel (C col)
  const int hi   = lane >> 5;

  const int wg     = blockIdx.x;       // 1024 blocks
  const int bb     = wg >> 5;          // image
  const int hwbase = (wg & 31) * 32;   // 32 consecutive pixels
  const float* xbase = xin + (size_t)bb * (CIN * HW) + hwbase + px;

  // ---- stage x into LDS (this wave's ct slice), y-phase consumption layout ----
  // entry (ct,rb,hi,px) holds c = ct*32 + 8*rb + 4*hi + {0,1,2,3}
#pragma unroll
  for (int rb = 0; rb < 4; ++rb) {
    int c0 = wv * 32 + 8 * rb + 4 * hi;
    u32x2 pk = { cvt_pk_bf16(xbase[c0 * HW],       xbase[(c0 + 1) * HW]),
                 cvt_pk_bf16(xbase[(c0 + 2) * HW], xbase[(c0 + 3) * HW]) };
    *(u32x2*)(xS + ((((wv * 4 + rb) * 2 + hi) * 32 + px) << 1)) = pk;
  }

  // ---- init hA = bf16(1/512) (exact): 8192 u32 words / 512 threads ----
  {
    unsigned* h32 = (unsigned*)hA;
#pragma unroll
    for (int g = 0; g < 16; ++g) h32[tid + (g << 9)] = 0x3B003B00u;  // two bf16(2^-9)
  }

  // persistent fp32 h: j = (wv*2+n)*32 + (r&3)+8*(r>>2)+4*hi, col = hwbase+px
  f32x16 hreg[2];   // [n]
#pragma unroll
  for (int n = 0; n < 2; ++n)
#pragma unroll
    for (int r = 0; r < 16; ++r) hreg[n][r] = 1.0f / 512.0f;

  const unsigned short* w1w = w1 + (size_t)wv * (32 * 512) + lane * 8;       // ct = wv
  const unsigned short* w2w = w2 + (size_t)(wv * 2) * (16 * 512) + lane * 8; // jt = 2wv+n
  const unsigned short* hAr = hA + lane * 8;
  const unsigned short* yFr = yF + lane * 8;

  __syncthreads();

  for (int it = 0; it < ITERS; ++it) {
    // ===== GEMM1 (swapped): rec^T[c][px] = sum_j W[j][c] h[px][j] =====
    // One (ct = wv) chain per wave: 32 MFMA, acc1 = 16 AGPR.
    f32x16 acc1;
#pragma unroll
    for (int r = 0; r < 16; ++r) acc1[r] = 0.0f;

#pragma unroll 4
    for (int kt = 0; kt < 32; ++kt) {
      bf16x8 a = *(const bf16x8*)(w1w + kt * 512);
      bf16x8 b = *(const bf16x8*)(hAr + kt * 512);
      acc1 = __builtin_amdgcn_mfma_f32_32x32x16_bf16(a, b, acc1, 0, 0, 0);
    }

    // y = x / (rec + 1e-20) -> yF (GEMM2 B-frag layout), single b64 stores
    // c = wv*32 + 8*rb + 4*hi + t ; kt2 = wv*2+(rb>>1); slot=((rb&1)<<5)+px; i=4*hi+t
#pragma unroll
    for (int rb = 0; rb < 4; ++rb) {
      u32x2 xp = *(const u32x2*)(xS + ((((wv * 4 + rb) * 2 + hi) * 32 + px) << 1));
      float x0 = __builtin_bit_cast(float, xp.x << 16);
      float x1 = __builtin_bit_cast(float, xp.x & 0xffff0000u);
      float x2 = __builtin_bit_cast(float, xp.y << 16);
      float x3 = __builtin_bit_cast(float, xp.y & 0xffff0000u);
      float y0 = x0 * __builtin_amdgcn_rcpf(acc1[4 * rb + 0] + 1e-20f);
      float y1 = x1 * __builtin_amdgcn_rcpf(acc1[4 * rb + 1] + 1e-20f);
      float y2 = x2 * __builtin_amdgcn_rcpf(acc1[4 * rb + 2] + 1e-20f);
      float y3 = x3 * __builtin_amdgcn_rcpf(acc1[4 * rb + 3] + 1e-20f);
      int kt2 = wv * 2 + (rb >> 1);
      u32x2 pk = { cvt_pk_bf16(y0, y1), cvt_pk_bf16(y2, y3) };
      *(u32x2*)(yF + ((kt2 * 64 + ((rb & 1) << 5) + px) << 3) + (hi << 2)) = pk;
    }
    __syncthreads();   // (a) yF complete

    // ===== GEMM2 (swapped): t^T[j][px] = sum_c W[j][c] y[px][c] =====
    // jt pair {2wv, 2wv+1}; per kt: 1 b-read (LDS) -> 2 MFMAs. acc2 = 32 AGPR.
    f32x16 acc2[2];
#pragma unroll
    for (int n = 0; n < 2; ++n)
#pragma unroll
      for (int r = 0; r < 16; ++r) acc2[n][r] = 0.0f;

#pragma unroll 2
    for (int kt = 0; kt < 16; ++kt) {
      bf16x8 b  = *(const bf16x8*)(yFr + kt * 512);
      bf16x8 a0 = *(const bf16x8*)(w2w + kt * 512);
      bf16x8 a1 = *(const bf16x8*)(w2w + (16 + kt) * 512);
      acc2[0] = __builtin_amdgcn_mfma_f32_32x32x16_bf16(a0, b, acc2[0], 0, 0, 0);
      acc2[1] = __builtin_amdgcn_mfma_f32_32x32x16_bf16(a1, b, acc2[1], 0, 0, 0);
    }

    // ===== h *= t ; per-px partial sums =====
    float psum = 0.0f;
#pragma unroll
    for (int n = 0; n < 2; ++n)
#pragma unroll
      for (int r = 0; r < 16; ++r) {
        float hn = hreg[n][r] * acc2[n][r];
        hreg[n][r] = hn;
        psum += hn;
      }
    psum += __shfl_xor(psum, 32, 64);   // fold complementary row-half (same px)
    if (lane < 32) red[px * 12 + wv] = psum;
    __syncthreads();   // (b) red visible

    // sum 8 wave-partials per px: 2x f32x4 (stride 12 -> 16B aligned)
    const float* rp = red + px * 12;
    f32x4 s0 = *(const f32x4*)(rp + 0);
    f32x4 s1 = *(const f32x4*)(rp + 4);
    float s = (s0[0] + s0[1] + s0[2] + s0[3]) + (s1[0] + s1[1] + s1[2] + s1[3]);
    float inv = __builtin_amdgcn_rcpf(s + 1e-19f);

    if (it < ITERS - 1) {
      // normalize + restage h into hA (GEMM1 B-frag layout), single b64 stores
      // j = (wv*2+n)*32 + 8*rb + 4*hi + t ; kt = (wv*2+n)*2+(rb>>1)
#pragma unroll
      for (int n = 0; n < 2; ++n)
#pragma unroll
        for (int rb = 0; rb < 4; ++rb) {
          float h0 = hreg[n][4 * rb + 0] * inv;
          float h1 = hreg[n][4 * rb + 1] * inv;
          float h2 = hreg[n][4 * rb + 2] * inv;
          float h3 = hreg[n][4 * rb + 3] * inv;
          hreg[n][4 * rb + 0] = h0; hreg[n][4 * rb + 1] = h1;
          hreg[n][4 * rb + 2] = h2; hreg[n][4 * rb + 3] = h3;
          int kt = (wv * 2 + n) * 2 + (rb >> 1);
          u32x2 pk = { cvt_pk_bf16(h0, h1), cvt_pk_bf16(h2, h3) };
          *(u32x2*)(hA + ((kt * 64 + ((rb & 1) << 5) + px) << 3) + (hi << 2)) = pk;
        }
    } else {
      // final store fp32: out[b][j][hw]; lanes 0..31 = consecutive px -> coalesced
      float* obase = out + (size_t)bb * (COUT * HW) + hwbase + px;
#pragma unroll
      for (int n = 0; n < 2; ++n)
#pragma unroll
        for (int r = 0; r < 16; ++r) {
          int j = (wv * 2 + n) * 32 + (r & 3) + 8 * (r >> 2) + 4 * hi;
          obase[j * HW] = hreg[n][r] * inv;
        }
    }
    __syncthreads();   // (c) hA ready / yF & red reusable
  }
}

extern "C" void kernel_launch(void* const* d_in, const int* in_sizes, int n_in,
                              void* d_out, int out_size, void* d_ws, size_t ws_size,
                              hipStream_t stream) {
  const float* x = (const float*)d_in[0];   // [32,256,32,32]
  const float* w = (const float*)d_in[1];   // [512,256]
  unsigned short* w1 = (unsigned short*)d_ws;          // 256 KB
  unsigned short* w2 = w1 + COUT * CIN;                // 256 KB
  float* out = (float*)d_out;

  prep_weights<<<dim3(512), dim3(256), 0, stream>>>(w, w1, w2);
  nnmf_kernel<<<dim3(1024), dim3(512), 0, stream>>>(x, w1, w2, out);
}

// Round 9
// 451.296 us; speedup vs baseline: 1.1764x; 1.1764x over previous
//
#include <hip/hip_runtime.h>

#define CIN   256
#define COUT  512
#define HW    1024     // H*W = 32*32
#define ITERS 20

typedef __attribute__((ext_vector_type(8)))  short bf16x8;
typedef __attribute__((ext_vector_type(4)))  float f32x4;
typedef __attribute__((ext_vector_type(16))) float f32x16;
typedef __attribute__((ext_vector_type(2)))  unsigned u32x2;

__device__ __forceinline__ unsigned short f2b(float x) {
  unsigned b = __builtin_bit_cast(unsigned, x);
  unsigned r = (b + 0x7FFFu + ((b >> 16) & 1u)) >> 16;   // RNE
  return (unsigned short)r;
}
// packed f32x2 -> bf16x2 (RNE), lo = a, hi = b
__device__ __forceinline__ unsigned cvt_pk_bf16(float a, float b) {
  unsigned r;
  asm("v_cvt_pk_bf16_f32 %0, %1, %2" : "=v"(r) : "v"(a), "v"(b));
  return r;
}

// 32x32x16 MFMA fragment conventions (gfx950):
//  A-frag: lane l holds row m = l&31,  k = (l>>5)*8 + i  (i=0..7)
//  B-frag: lane l holds col n = l&31,  k = (l>>5)*8 + i
//  C/D   : col = lane&31, row = (r&3) + 8*(r>>2) + 4*(lane>>5), r in [0,16)
//
// Both GEMMs computed TRANSPOSED (A = weights, B = h/y, cols = pixels).
//
// w1: GEMM1 A-frags [ct:8][kt:32][lane:64][i:8];  c = ct*32+(l&31), j = kt*16+(l>>5)*8+i
// w2: GEMM2 A-frags [jt:16][kt:16][lane:64][i:8]; j = jt*32+(l&31), c = kt*16+(l>>5)*8+i
__global__ __launch_bounds__(256) void prep_weights(const float* __restrict__ w,
                                                    unsigned short* __restrict__ w1,
                                                    unsigned short* __restrict__ w2) {
  int f = blockIdx.x * 256 + threadIdx.x;   // [0, 131072)
  {
    int i = f & 7, l = (f >> 3) & 63, kt = (f >> 9) & 31, ct = f >> 14;
    int c = ct * 32 + (l & 31);
    int j = kt * 16 + ((l >> 5) << 3) + i;
    w1[f] = f2b(w[j * CIN + c]);
  }
  {
    int i = f & 7, l = (f >> 3) & 63, kt = (f >> 9) & 15, jt = f >> 13;
    int j = jt * 32 + (l & 31);
    int c = kt * 16 + ((l >> 5) << 3) + i;
    w2[f] = f2b(w[j * CIN + c]);
  }
}

// R9 = R7 (best: 479us; 64px / 1024thr / 16 waves / 4 waves/SIMD, spill-free) plus:
//  1) barriers 3 -> 2 per iter: hA holds UNNORMALIZED u = h*t; per-lane inv registers
//     (invv0/invv1, one per px-tile) carry the normalization across the barrier.
//     y-phase: y = x*rcp(inv*acc1 + 1e-20)  [== x/(h@W+eps), exact]
//     h-update: hn = hreg*inv*acc2          [== h*t, exact; bounded ~0.25]
//     restage writes hn directly, INSIDE the GEMM2 phase (hA is dead between
//     barrier (a) and next GEMM1 -> race-free), killing the serial tail.
//  2) GEMM1 split into 2 accumulator chains (kt 0-15 / 16-31) for MFMA ILP.
// R8 lesson: never shrink the px tile (weight L2 traffic dominates decorrelation).
__global__ __launch_bounds__(1024, 4) void nnmf_kernel(const float* __restrict__ xin,
                                                       const unsigned short* __restrict__ w1,
                                                       const unsigned short* __restrict__ w2,
                                                       float* __restrict__ out) {
  __shared__ __align__(16) unsigned short hA[2 * 32 * 512]; // 64KB  B-frags GEMM1 (k=j), per px-tile
  __shared__ __align__(16) unsigned short yF[2 * 16 * 512]; // 32KB  B-frags GEMM2 (k=c), per px-tile
  __shared__ __align__(16) unsigned xS[2 * 8 * 4 * 2 * 32 * 2]; // 32KB bf16 x, [pt][ct][rb][hi][px][2]
  __shared__ float red[2 * 32 * 20];                        // 5KB per-(pt,px) partials, stride 20

  const int tid  = threadIdx.x;
  const int wv   = tid >> 6;      // 0..15
  const int lane = tid & 63;
  const int px   = lane & 31;     // pixel within tile (C col)
  const int hi   = lane >> 5;

  const int ct = wv >> 1;         // GEMM1 / y-phase: channel slice
  const int pA = wv & 1;          // GEMM1 / y-phase: pixel tile
  const int jt = wv;              // GEMM2 / restage / store: output-channel slice

  const int wg     = blockIdx.x;       // 512 blocks
  const int bb     = wg >> 4;          // image
  const int hwbase = (wg & 15) * 64;   // 64 consecutive pixels
  const float* xbase = xin + (size_t)bb * (CIN * HW) + hwbase + px;

  // ---- stage x into LDS (only this wave's (pA,ct) slice), y-phase layout ----
#pragma unroll
  for (int rb = 0; rb < 4; ++rb) {
    int c0 = ct * 32 + 8 * rb + 4 * hi;
    const float* xp = xbase + pA * 32;
    u32x2 pk = { cvt_pk_bf16(xp[c0 * HW],       xp[(c0 + 1) * HW]),
                 cvt_pk_bf16(xp[(c0 + 2) * HW], xp[(c0 + 3) * HW]) };
    *(u32x2*)(xS + (((((pA * 8 + ct) * 4 + rb) * 2 + hi) * 32 + px) << 1)) = pk;
  }

  // ---- init hA = bf16(1/512) (exact): 16384 u32 words / 1024 threads ----
  {
    unsigned* h32 = (unsigned*)hA;
#pragma unroll
    for (int g = 0; g < 16; ++g) h32[tid + (g << 10)] = 0x3B003B00u;  // two bf16(2^-9)
  }

  // persistent fp32 u (unnormalized h): j = wv*32 + (r&3)+8*(r>>2)+4*hi
  f32x16 hreg[2];   // [pt]
#pragma unroll
  for (int pt = 0; pt < 2; ++pt)
#pragma unroll
    for (int r = 0; r < 16; ++r) hreg[pt][r] = 1.0f / 512.0f;

  float invv0 = 1.0f, invv1 = 1.0f;   // per-px normalization for hreg/hA content

  const unsigned short* w1w = w1 + (size_t)ct * (32 * 512) + lane * 8;
  const unsigned short* w2w = w2 + (size_t)jt * (16 * 512) + lane * 8;
  const unsigned short* hAp = hA + pA * (32 * 512) + lane * 8;
  const unsigned short* yFr = yF + lane * 8;

  __syncthreads();

  for (int it = 0; it < ITERS; ++it) {
    // ===== GEMM1 (swapped): rec'[c][px] = sum_j W[j][c] u[px][j] =====
    // Two independent chains (kt halves) for MFMA ILP; 32 AGPR.
    f32x16 acc1a, acc1b;
#pragma unroll
    for (int r = 0; r < 16; ++r) { acc1a[r] = 0.0f; acc1b[r] = 0.0f; }

#pragma unroll 2
    for (int kt = 0; kt < 16; ++kt) {
      bf16x8 a0 = *(const bf16x8*)(w1w + kt * 512);
      bf16x8 b0 = *(const bf16x8*)(hAp + kt * 512);
      bf16x8 a1 = *(const bf16x8*)(w1w + (16 + kt) * 512);
      bf16x8 b1 = *(const bf16x8*)(hAp + (16 + kt) * 512);
      acc1a = __builtin_amdgcn_mfma_f32_32x32x16_bf16(a0, b0, acc1a, 0, 0, 0);
      acc1b = __builtin_amdgcn_mfma_f32_32x32x16_bf16(a1, b1, acc1b, 0, 0, 0);
    }

    // y = x * rcp(inv*rec' + 1e-20) -> yF (GEMM2 B-frag layout), single b64 stores
    {
      float ainv = pA ? invv1 : invv0;   // inv for this wave's px tile (uniform select)
#pragma unroll
      for (int rb = 0; rb < 4; ++rb) {
        u32x2 xp = *(const u32x2*)(xS + (((((pA * 8 + ct) * 4 + rb) * 2 + hi) * 32 + px) << 1));
        float x0 = __builtin_bit_cast(float, xp.x << 16);
        float x1 = __builtin_bit_cast(float, xp.x & 0xffff0000u);
        float x2 = __builtin_bit_cast(float, xp.y << 16);
        float x3 = __builtin_bit_cast(float, xp.y & 0xffff0000u);
        float r0 = acc1a[4 * rb + 0] + acc1b[4 * rb + 0];
        float r1 = acc1a[4 * rb + 1] + acc1b[4 * rb + 1];
        float r2 = acc1a[4 * rb + 2] + acc1b[4 * rb + 2];
        float r3 = acc1a[4 * rb + 3] + acc1b[4 * rb + 3];
        float y0 = x0 * __builtin_amdgcn_rcpf(ainv * r0 + 1e-20f);
        float y1 = x1 * __builtin_amdgcn_rcpf(ainv * r1 + 1e-20f);
        float y2 = x2 * __builtin_amdgcn_rcpf(ainv * r2 + 1e-20f);
        float y3 = x3 * __builtin_amdgcn_rcpf(ainv * r3 + 1e-20f);
        int kt2 = ct * 2 + (rb >> 1);
        u32x2 pk = { cvt_pk_bf16(y0, y1), cvt_pk_bf16(y2, y3) };
        *(u32x2*)(yF + (((pA * 16 + kt2) * 64 + ((rb & 1) << 5) + px) << 3) + (hi << 2)) = pk;
      }
    }
    __syncthreads();   // (a) yF complete; hA now dead until restage

    // ===== GEMM2 (swapped): t[j][px] = sum_c W[j][c] y[px][c] =====
    // One jt per wave, both pt; w2 frag loaded once -> 2 MFMAs. 32 AGPR.
    f32x16 acc2[2];
#pragma unroll
    for (int pt = 0; pt < 2; ++pt)
#pragma unroll
      for (int r = 0; r < 16; ++r) acc2[pt][r] = 0.0f;

#pragma unroll 2
    for (int kt = 0; kt < 16; ++kt) {
      bf16x8 a  = *(const bf16x8*)(w2w + kt * 512);
      bf16x8 b0 = *(const bf16x8*)(yFr + kt * 512);          // px-tile 0
      bf16x8 b1 = *(const bf16x8*)(yFr + (16 + kt) * 512);   // px-tile 1
      acc2[0] = __builtin_amdgcn_mfma_f32_32x32x16_bf16(a, b0, acc2[0], 0, 0, 0);
      acc2[1] = __builtin_amdgcn_mfma_f32_32x32x16_bf16(a, b1, acc2[1], 0, 0, 0);
    }

    // ===== u_new = (u*inv)*t = h*t ; per-(pt,px) partial sums =====
    float psum0 = 0.0f, psum1 = 0.0f;
#pragma unroll
    for (int r = 0; r < 16; ++r) {
      float hn0 = hreg[0][r] * invv0 * acc2[0][r];
      float hn1 = hreg[1][r] * invv1 * acc2[1][r];
      hreg[0][r] = hn0;
      hreg[1][r] = hn1;
      psum0 += hn0;
      psum1 += hn1;
    }
    psum0 += __shfl_xor(psum0, 32, 64);   // fold complementary row-half (same px)
    psum1 += __shfl_xor(psum1, 32, 64);
    if (lane < 32) {
      red[(0 * 32 + px) * 20 + wv] = psum0;
      red[(1 * 32 + px) * 20 + wv] = psum1;
    }

    if (it < ITERS - 1) {
      // restage u_new into hA (GEMM1 B-frag layout) — no normalization needed,
      // overlapped with other waves' GEMM2/psum (hA dead since barrier (a)).
#pragma unroll
      for (int pt = 0; pt < 2; ++pt)
#pragma unroll
        for (int rb = 0; rb < 4; ++rb) {
          float h0 = hreg[pt][4 * rb + 0];
          float h1 = hreg[pt][4 * rb + 1];
          float h2 = hreg[pt][4 * rb + 2];
          float h3 = hreg[pt][4 * rb + 3];
          int kt = wv * 2 + (rb >> 1);
          u32x2 pk = { cvt_pk_bf16(h0, h1), cvt_pk_bf16(h2, h3) };
          *(u32x2*)(hA + (((pt * 32 + kt) * 64 + ((rb & 1) << 5) + px) << 3) + (hi << 2)) = pk;
        }
    }
    __syncthreads();   // (b) red + hA ready; yF reusable

    // fresh inv from red: sum 16 wave-partials per (pt,px)
    {
      const float* rp0 = red + (0 * 32 + px) * 20;
      f32x4 a0 = *(const f32x4*)(rp0 + 0);
      f32x4 a1 = *(const f32x4*)(rp0 + 4);
      f32x4 a2 = *(const f32x4*)(rp0 + 8);
      f32x4 a3 = *(const f32x4*)(rp0 + 12);
      float s0 = (a0[0]+a0[1]+a0[2]+a0[3]) + (a1[0]+a1[1]+a1[2]+a1[3])
               + (a2[0]+a2[1]+a2[2]+a2[3]) + (a3[0]+a3[1]+a3[2]+a3[3]);
      invv0 = __builtin_amdgcn_rcpf(s0 + 1e-19f);
      const float* rp1 = red + (1 * 32 + px) * 20;
      f32x4 b0 = *(const f32x4*)(rp1 + 0);
      f32x4 b1 = *(const f32x4*)(rp1 + 4);
      f32x4 b2 = *(const f32x4*)(rp1 + 8);
      f32x4 b3 = *(const f32x4*)(rp1 + 12);
      float s1 = (b0[0]+b0[1]+b0[2]+b0[3]) + (b1[0]+b1[1]+b1[2]+b1[3])
               + (b2[0]+b2[1]+b2[2]+b2[3]) + (b3[0]+b3[1]+b3[2]+b3[3]);
      invv1 = __builtin_amdgcn_rcpf(s1 + 1e-19f);
    }
  }

  // final store fp32: out[b][j][hw] = u * inv ; lanes = consecutive px -> coalesced
  {
    float* obase = out + (size_t)bb * (COUT * HW) + hwbase + px;
#pragma unroll
    for (int pt = 0; pt < 2; ++pt) {
      float fin = pt ? invv1 : invv0;
#pragma unroll
      for (int r = 0; r < 16; ++r) {
        int j = wv * 32 + (r & 3) + 8 * (r >> 2) + 4 * hi;
        obase[j * HW + pt * 32] = hreg[pt][r] * fin;
      }
    }
  }
}

extern "C" void kernel_launch(void* const* d_in, const int* in_sizes, int n_in,
                              void* d_out, int out_size, void* d_ws, size_t ws_size,
                              hipStream_t stream) {
  const float* x = (const float*)d_in[0];   // [32,256,32,32]
  const float* w = (const float*)d_in[1];   // [512,256]
  unsigned short* w1 = (unsigned short*)d_ws;          // 256 KB
  unsigned short* w2 = w1 + COUT * CIN;                // 256 KB
  float* out = (float*)d_out;

  prep_weights<<<dim3(512), dim3(256), 0, stream>>>(w, w1, w2);
  nnmf_kernel<<<dim3(512), dim3(1024), 0, stream>>>(x, w1, w2, out);
}